// Round 3
// baseline (2983.596 us; speedup 1.0000x reference)
//
#include <hip/hip_runtime.h>
#include <stdint.h>
#include <math.h>

#define HW   4096
#define NB   8
#define NC   512
#define C2   256
#define PT   32     // p-tile per block in argmax kernel

// ---------- ws layout (bytes) ----------
#define WS_PACKED 0         // u64 packed[8*4096]            = 262144
#define WS_INVN   262144    // f32 invn[8*4096]              = 131072
#define WS_Q0     393216    // i32 q0list[4096]              = 16384
#define WS_P1     409600    // i32 p1list[4096]              = 16384
#define WS_CNT    425984    // i32 cnt[2]
#define WS_IDX    427008    // i32 idx[8*4096]               = 131072

__device__ __forceinline__ unsigned long long mkkey(float v, unsigned q) {
    unsigned u = __float_as_uint(v);
    u = (u & 0x80000000u) ? ~u : (u | 0x80000000u);   // monotone float -> u32
    return ((unsigned long long)u << 32) | (unsigned long long)(0xFFFFFFFFu - q);
}

// --- 1. deterministic sorted compaction of flag into p1 (flag==1) / q0 (flag==0)
__global__ void compact_kernel(const int* __restrict__ flag, int* __restrict__ q0,
                               int* __restrict__ p1, int* __restrict__ cnt) {
    __shared__ int c1s[256];
    int t = threadIdx.x;
    int f[16]; int n1 = 0;
    #pragma unroll
    for (int j = 0; j < 16; ++j) { f[j] = flag[t*16 + j]; n1 += (f[j] == 1); }
    c1s[t] = n1;
    __syncthreads();
    if (t == 0) {
        int run = 0;
        for (int i = 0; i < 256; ++i) { int v = c1s[i]; c1s[i] = run; run += v; }
        cnt[0] = run;          // n1
        cnt[1] = HW - run;     // n0
    }
    __syncthreads();
    int b1 = c1s[t];
    int b0 = t*16 - c1s[t];
    for (int j = 0; j < 16; ++j) {
        int i = t*16 + j;
        if (f[j] == 1) p1[b1++] = i; else q0[b0++] = i;
    }
}

// --- 2. inv norms of latter columns
__global__ void norm_kernel(const float* __restrict__ x, float* __restrict__ invn) {
    int b = blockIdx.y;
    int q = blockIdx.x * 256 + threadIdx.x;
    const float* lf = x + ((size_t)b * NC + C2) * HW + q;
    float s = 0.f;
    #pragma unroll 8
    for (int c = 0; c < C2; ++c) {
        float v = lf[c * HW];
        s = fmaf(v, v, s);
    }
    invn[b * HW + q] = 1.0f / fmaxf(sqrtf(s), 1e-8f);
}

// --- 3. cos + argmax over unmasked q, merged via packed atomicMax
//     grid: (HW/PT tiles, 8 q-chunks of 512, NB).  One pass per block,
//     software-prefetched gathers, 4 blocks/CU residency.
__global__ void __launch_bounds__(256, 4) argmax_kernel(
        const float* __restrict__ x, const float* __restrict__ invn,
        const int* __restrict__ q0, const int* __restrict__ p1,
        const int* __restrict__ cnt, unsigned long long* __restrict__ packed) {
    int tile  = blockIdx.x;
    int chunk = blockIdx.y;
    int b     = blockIdx.z;
    int n1 = cnt[0], n0 = cnt[1];
    if (tile * PT >= n1) return;
    if ((chunk << 9) >= n0) return;

    __shared__ float sff[256][PT];   // ff tile: [c][p] 32 KB
    __shared__ int   sp[PT];

    int t = threadIdx.x;
    if (t < PT) sp[t] = (tile * PT + t < n1) ? p1[tile * PT + t] : -1;
    __syncthreads();

    const float* xb = x + (size_t)b * NC * HW;
    #pragma unroll
    for (int k = 0; k < 32; ++k) {      // 8192 elems / 256 threads
        int i = t + (k << 8);
        int c = i >> 5, j = i & 31;
        int p = sp[j];
        sff[c][j] = (p >= 0) ? xb[c * HW + p] : 0.f;
    }
    __syncthreads();

    int tp = t >> 6;   // wave id -> 8-p sub-tile
    int tq = t & 63;   // lane    -> q
    const float* lfb = xb + C2 * HW;

    int qi[8], qj[8];
    #pragma unroll
    for (int j = 0; j < 8; ++j) {
        qi[j] = (chunk << 9) + (j << 6) + tq;
        qj[j] = (qi[j] < n0) ? q0[qi[j]] : 0;
    }

    float acc[8][8];
    #pragma unroll
    for (int pi = 0; pi < 8; ++pi)
        #pragma unroll
        for (int j = 0; j < 8; ++j) acc[pi][j] = 0.f;

    const float* row = lfb;
    float bv[8];
    #pragma unroll
    for (int j = 0; j < 8; ++j) bv[j] = row[qj[j]];

    #pragma unroll 2
    for (int c = 0; c < 255; ++c) {
        const float* nrow = row + HW;
        float bvn[8];
        #pragma unroll
        for (int j = 0; j < 8; ++j) bvn[j] = nrow[qj[j]];   // prefetch c+1
        const float4* arow = (const float4*)&sff[c][tp * 8];
        float4 a0 = arow[0], a1 = arow[1];
        float av[8] = {a0.x, a0.y, a0.z, a0.w, a1.x, a1.y, a1.z, a1.w};
        #pragma unroll
        for (int pi = 0; pi < 8; ++pi)
            #pragma unroll
            for (int j = 0; j < 8; ++j)
                acc[pi][j] = fmaf(av[pi], bv[j], acc[pi][j]);
        #pragma unroll
        for (int j = 0; j < 8; ++j) bv[j] = bvn[j];
        row = nrow;
    }
    {   // c = 255 (no prefetch)
        const float4* arow = (const float4*)&sff[255][tp * 8];
        float4 a0 = arow[0], a1 = arow[1];
        float av[8] = {a0.x, a0.y, a0.z, a0.w, a1.x, a1.y, a1.z, a1.w};
        #pragma unroll
        for (int pi = 0; pi < 8; ++pi)
            #pragma unroll
            for (int j = 0; j < 8; ++j)
                acc[pi][j] = fmaf(av[pi], bv[j], acc[pi][j]);
    }

    float best[8];
    int   bq[8];
    #pragma unroll
    for (int pi = 0; pi < 8; ++pi) { best[pi] = -INFINITY; bq[pi] = 0x7FFFFFFF; }

    #pragma unroll
    for (int j = 0; j < 8; ++j) {
        if (qi[j] >= n0) continue;
        float sc = invn[b * HW + qj[j]];
        #pragma unroll
        for (int pi = 0; pi < 8; ++pi) {
            float cv = acc[pi][j] * sc;
            if (cv > best[pi] || (cv == best[pi] && qj[j] < bq[pi])) {
                best[pi] = cv; bq[pi] = qj[j];
            }
        }
    }

    // wave reduce (all 64 lanes share the same 8 p's)
    #pragma unroll
    for (int m = 1; m < 64; m <<= 1) {
        #pragma unroll
        for (int pi = 0; pi < 8; ++pi) {
            float ov = __shfl_xor(best[pi], m);
            int   oq = __shfl_xor(bq[pi], m);
            if (ov > best[pi] || (ov == best[pi] && oq < bq[pi])) {
                best[pi] = ov; bq[pi] = oq;
            }
        }
    }
    if (tq == 0) {
        #pragma unroll
        for (int pi = 0; pi < 8; ++pi) {
            int p = sp[tp * 8 + pi];
            if (p >= 0)
                atomicMax(&packed[(size_t)b * HW + p], mkkey(best[pi], (unsigned)bq[pi]));
        }
    }
}

// --- 4. decode packed keys -> idx
__global__ void decode_kernel(const unsigned long long* __restrict__ packed,
                              const int* __restrict__ flag, int* __restrict__ idx) {
    int b = blockIdx.y, p = blockIdx.x * 256 + threadIdx.x;
    int q = 0;
    if (flag[p] == 1) {
        unsigned low = (unsigned)(packed[(size_t)b * HW + p] & 0xFFFFFFFFull);
        q = (int)((0xFFFFFFFFu - low) & (HW - 1));
    }
    idx[b * HW + p] = q;
}

// --- 5. copy former+latter -> out channels [0,512)
__global__ void copy_kernel(const float4* __restrict__ x4, float4* __restrict__ out4) {
    size_t i = (size_t)blockIdx.x * 256 + threadIdx.x;
    if (i >= (size_t)NB * NC * (HW / 4)) return;
    size_t p4 = i & 1023;
    size_t c  = (i >> 10) & 511;
    size_t b  = i >> 19;
    out4[(b * 768 + c) * 1024 + p4] = x4[i];
}

// --- 6. shift writeback: out[b, 512+c, p] = flag[p] ? lf[b, c, idx[b,p]] : 0
__global__ void shift_kernel(const float* __restrict__ x, const int* __restrict__ flag,
                             const int* __restrict__ idx, float* __restrict__ out) {
    int cc = blockIdx.x, b = blockIdx.y;
    const float* lfrow = x + ((size_t)b * NC + C2 + cc) * HW;
    float*       orow  = out + ((size_t)b * 768 + 512 + cc) * HW;
    const int*   idxb  = idx + b * HW;
    for (int p = threadIdx.x; p < HW; p += 256) {
        float v = 0.f;
        if (flag[p] == 1) v = lfrow[idxb[p]];
        orow[p] = v;
    }
}

extern "C" void kernel_launch(void* const* d_in, const int* in_sizes, int n_in,
                              void* d_out, int out_size, void* d_ws, size_t ws_size,
                              hipStream_t stream) {
    const float* x    = (const float*)d_in[0];
    const int*   flag = (const int*)d_in[1];
    float*       out  = (float*)d_out;
    char*        ws   = (char*)d_ws;

    unsigned long long* packed = (unsigned long long*)(ws + WS_PACKED);
    float* invn = (float*)(ws + WS_INVN);
    int*   q0   = (int*)(ws + WS_Q0);
    int*   p1   = (int*)(ws + WS_P1);
    int*   cnt  = (int*)(ws + WS_CNT);
    int*   idx  = (int*)(ws + WS_IDX);

    hipMemsetAsync(packed, 0, (size_t)NB * HW * sizeof(unsigned long long), stream);

    compact_kernel<<<1, 256, 0, stream>>>(flag, q0, p1, cnt);
    norm_kernel<<<dim3(HW / 256, NB), 256, 0, stream>>>(x, invn);
    copy_kernel<<<(NB * NC * (HW / 4) + 255) / 256, 256, 0, stream>>>((const float4*)x, (float4*)out);
    argmax_kernel<<<dim3(HW / PT, 8, NB), 256, 0, stream>>>(x, invn, q0, p1, cnt, packed);
    decode_kernel<<<dim3(HW / 256, NB), 256, 0, stream>>>(packed, flag, idx);
    shift_kernel<<<dim3(C2, NB), 256, 0, stream>>>(x, flag, idx, out);
}

// Round 4
// 331.385 us; speedup vs baseline: 9.0034x; 9.0034x over previous
//
#include <hip/hip_runtime.h>
#include <stdint.h>
#include <math.h>

#define HW   4096
#define NB   8
#define NC   512
#define C2   256
#define PT   32     // p-tile per block in argmax kernel

// ---------- ws layout (bytes) ----------
#define WS_PACKED 0         // u64 packed[8*4096]            = 262144
#define WS_INVN   262144    // f32 invn[8*4096]              = 131072
#define WS_Q0     393216    // i32 q0list[4096]              = 16384
#define WS_P1     409600    // i32 p1list[4096]              = 16384
#define WS_CNT    425984    // i32 cnt[2]
#define WS_IDX    427008    // i32 idx[8*4096]               = 131072

__device__ __forceinline__ unsigned long long mkkey(float v, unsigned q) {
    unsigned u = __float_as_uint(v);
    u = (u & 0x80000000u) ? ~u : (u | 0x80000000u);   // monotone float -> u32
    return ((unsigned long long)u << 32) | (unsigned long long)(0xFFFFFFFFu - q);
}

// --- 1. deterministic sorted compaction of flag into p1 (flag==1) / q0 (flag==0)
__global__ void compact_kernel(const int* __restrict__ flag, int* __restrict__ q0,
                               int* __restrict__ p1, int* __restrict__ cnt) {
    __shared__ int c1s[256];
    int t = threadIdx.x;
    int f[16]; int n1 = 0;
    #pragma unroll
    for (int j = 0; j < 16; ++j) { f[j] = flag[t*16 + j]; n1 += (f[j] == 1); }
    c1s[t] = n1;
    __syncthreads();
    if (t == 0) {
        int run = 0;
        for (int i = 0; i < 256; ++i) { int v = c1s[i]; c1s[i] = run; run += v; }
        cnt[0] = run;          // n1
        cnt[1] = HW - run;     // n0
    }
    __syncthreads();
    int b1 = c1s[t];
    int b0 = t*16 - c1s[t];
    for (int j = 0; j < 16; ++j) {
        int i = t*16 + j;
        if (f[j] == 1) p1[b1++] = i; else q0[b0++] = i;
    }
}

// --- 2. inv norms of latter columns
__global__ void norm_kernel(const float* __restrict__ x, float* __restrict__ invn) {
    int b = blockIdx.y;
    int q = blockIdx.x * 256 + threadIdx.x;
    const float* lf = x + ((size_t)b * NC + C2) * HW + q;
    float s = 0.f;
    #pragma unroll 8
    for (int c = 0; c < C2; ++c) {
        float v = lf[c * HW];
        s = fmaf(v, v, s);
    }
    invn[b * HW + q] = 1.0f / fmaxf(sqrtf(s), 1e-8f);
}

// --- 3. cos + argmax over unmasked q, merged via packed atomicMax
//     grid: (HW/PT tiles, 8 q-chunks of 512, NB).  One pass per block,
//     software-prefetched gathers.  NOTE: no min-waves clamp in
//     launch_bounds — (256,4) forced VGPR=64 and spilled acc[8][8] to
//     scratch (13 GB HBM traffic, 7x regression in R3).
__global__ void __launch_bounds__(256) argmax_kernel(
        const float* __restrict__ x, const float* __restrict__ invn,
        const int* __restrict__ q0, const int* __restrict__ p1,
        const int* __restrict__ cnt, unsigned long long* __restrict__ packed) {
    int tile  = blockIdx.x;
    int chunk = blockIdx.y;
    int b     = blockIdx.z;
    int n1 = cnt[0], n0 = cnt[1];
    if (tile * PT >= n1) return;
    if ((chunk << 9) >= n0) return;

    __shared__ float sff[256][PT];   // ff tile: [c][p] 32 KB
    __shared__ int   sp[PT];

    int t = threadIdx.x;
    if (t < PT) sp[t] = (tile * PT + t < n1) ? p1[tile * PT + t] : -1;
    __syncthreads();

    const float* xb = x + (size_t)b * NC * HW;
    #pragma unroll
    for (int k = 0; k < 32; ++k) {      // 8192 elems / 256 threads
        int i = t + (k << 8);
        int c = i >> 5, j = i & 31;
        int p = sp[j];
        sff[c][j] = (p >= 0) ? xb[c * HW + p] : 0.f;
    }
    __syncthreads();

    int tp = t >> 6;   // wave id -> 8-p sub-tile
    int tq = t & 63;   // lane    -> q
    const float* lfb = xb + C2 * HW;

    int qi[8], qj[8];
    #pragma unroll
    for (int j = 0; j < 8; ++j) {
        qi[j] = (chunk << 9) + (j << 6) + tq;
        qj[j] = (qi[j] < n0) ? q0[qi[j]] : 0;
    }

    float acc[8][8];
    #pragma unroll
    for (int pi = 0; pi < 8; ++pi)
        #pragma unroll
        for (int j = 0; j < 8; ++j) acc[pi][j] = 0.f;

    const float* row = lfb;
    float bv[8];
    #pragma unroll
    for (int j = 0; j < 8; ++j) bv[j] = row[qj[j]];

    #pragma unroll 2
    for (int c = 0; c < 255; ++c) {
        const float* nrow = row + HW;
        float bvn[8];
        #pragma unroll
        for (int j = 0; j < 8; ++j) bvn[j] = nrow[qj[j]];   // prefetch c+1
        const float4* arow = (const float4*)&sff[c][tp * 8];
        float4 a0 = arow[0], a1 = arow[1];
        float av[8] = {a0.x, a0.y, a0.z, a0.w, a1.x, a1.y, a1.z, a1.w};
        #pragma unroll
        for (int pi = 0; pi < 8; ++pi)
            #pragma unroll
            for (int j = 0; j < 8; ++j)
                acc[pi][j] = fmaf(av[pi], bv[j], acc[pi][j]);
        #pragma unroll
        for (int j = 0; j < 8; ++j) bv[j] = bvn[j];
        row = nrow;
    }
    {   // c = 255 (no prefetch)
        const float4* arow = (const float4*)&sff[255][tp * 8];
        float4 a0 = arow[0], a1 = arow[1];
        float av[8] = {a0.x, a0.y, a0.z, a0.w, a1.x, a1.y, a1.z, a1.w};
        #pragma unroll
        for (int pi = 0; pi < 8; ++pi)
            #pragma unroll
            for (int j = 0; j < 8; ++j)
                acc[pi][j] = fmaf(av[pi], bv[j], acc[pi][j]);
    }

    float best[8];
    int   bq[8];
    #pragma unroll
    for (int pi = 0; pi < 8; ++pi) { best[pi] = -INFINITY; bq[pi] = 0x7FFFFFFF; }

    #pragma unroll
    for (int j = 0; j < 8; ++j) {
        if (qi[j] >= n0) continue;
        float sc = invn[b * HW + qj[j]];
        #pragma unroll
        for (int pi = 0; pi < 8; ++pi) {
            float cv = acc[pi][j] * sc;
            if (cv > best[pi] || (cv == best[pi] && qj[j] < bq[pi])) {
                best[pi] = cv; bq[pi] = qj[j];
            }
        }
    }

    // wave reduce (all 64 lanes share the same 8 p's)
    #pragma unroll
    for (int m = 1; m < 64; m <<= 1) {
        #pragma unroll
        for (int pi = 0; pi < 8; ++pi) {
            float ov = __shfl_xor(best[pi], m);
            int   oq = __shfl_xor(bq[pi], m);
            if (ov > best[pi] || (ov == best[pi] && oq < bq[pi])) {
                best[pi] = ov; bq[pi] = oq;
            }
        }
    }
    if (tq == 0) {
        #pragma unroll
        for (int pi = 0; pi < 8; ++pi) {
            int p = sp[tp * 8 + pi];
            if (p >= 0)
                atomicMax(&packed[(size_t)b * HW + p], mkkey(best[pi], (unsigned)bq[pi]));
        }
    }
}

// --- 4. decode packed keys -> idx
__global__ void decode_kernel(const unsigned long long* __restrict__ packed,
                              const int* __restrict__ flag, int* __restrict__ idx) {
    int b = blockIdx.y, p = blockIdx.x * 256 + threadIdx.x;
    int q = 0;
    if (flag[p] == 1) {
        unsigned low = (unsigned)(packed[(size_t)b * HW + p] & 0xFFFFFFFFull);
        q = (int)((0xFFFFFFFFu - low) & (HW - 1));
    }
    idx[b * HW + p] = q;
}

// --- 5. copy former+latter -> out channels [0,512)
__global__ void copy_kernel(const float4* __restrict__ x4, float4* __restrict__ out4) {
    size_t i = (size_t)blockIdx.x * 256 + threadIdx.x;
    if (i >= (size_t)NB * NC * (HW / 4)) return;
    size_t p4 = i & 1023;
    size_t c  = (i >> 10) & 511;
    size_t b  = i >> 19;
    out4[(b * 768 + c) * 1024 + p4] = x4[i];
}

// --- 6. shift writeback: out[b, 512+c, p] = flag[p] ? lf[b, c, idx[b,p]] : 0
__global__ void shift_kernel(const float* __restrict__ x, const int* __restrict__ flag,
                             const int* __restrict__ idx, float* __restrict__ out) {
    int cc = blockIdx.x, b = blockIdx.y;
    const float* lfrow = x + ((size_t)b * NC + C2 + cc) * HW;
    float*       orow  = out + ((size_t)b * 768 + 512 + cc) * HW;
    const int*   idxb  = idx + b * HW;
    for (int p = threadIdx.x; p < HW; p += 256) {
        float v = 0.f;
        if (flag[p] == 1) v = lfrow[idxb[p]];
        orow[p] = v;
    }
}

extern "C" void kernel_launch(void* const* d_in, const int* in_sizes, int n_in,
                              void* d_out, int out_size, void* d_ws, size_t ws_size,
                              hipStream_t stream) {
    const float* x    = (const float*)d_in[0];
    const int*   flag = (const int*)d_in[1];
    float*       out  = (float*)d_out;
    char*        ws   = (char*)d_ws;

    unsigned long long* packed = (unsigned long long*)(ws + WS_PACKED);
    float* invn = (float*)(ws + WS_INVN);
    int*   q0   = (int*)(ws + WS_Q0);
    int*   p1   = (int*)(ws + WS_P1);
    int*   cnt  = (int*)(ws + WS_CNT);
    int*   idx  = (int*)(ws + WS_IDX);

    hipMemsetAsync(packed, 0, (size_t)NB * HW * sizeof(unsigned long long), stream);

    compact_kernel<<<1, 256, 0, stream>>>(flag, q0, p1, cnt);
    norm_kernel<<<dim3(HW / 256, NB), 256, 0, stream>>>(x, invn);
    copy_kernel<<<(NB * NC * (HW / 4) + 255) / 256, 256, 0, stream>>>((const float4*)x, (float4*)out);
    argmax_kernel<<<dim3(HW / PT, 8, NB), 256, 0, stream>>>(x, invn, q0, p1, cnt, packed);
    decode_kernel<<<dim3(HW / 256, NB), 256, 0, stream>>>(packed, flag, idx);
    shift_kernel<<<dim3(C2, NB), 256, 0, stream>>>(x, flag, idx, out);
}

// Round 5
// 283.632 us; speedup vs baseline: 10.5192x; 1.1684x over previous
//
#include <hip/hip_runtime.h>
#include <stdint.h>
#include <math.h>

#define HW   4096
#define NB   8
#define NC   512
#define C2   256
#define PT   32     // p-tile per block in argmax kernel

// ---------- ws layout (bytes) ----------
#define WS_PACKED 0         // u64 packed[8*4096]            = 262144
#define WS_INVN   262144    // f32 invn[8*4096]              = 131072
#define WS_Q0     393216    // i32 q0list[4096]              = 16384
#define WS_P1     409600    // i32 p1list[4096]              = 16384
#define WS_CNT    425984    // i32 cnt[2]
#define WS_IDX    427008    // i32 idx[8*4096]               = 131072

__device__ __forceinline__ unsigned long long mkkey(float v, unsigned q) {
    unsigned u = __float_as_uint(v);
    u = (u & 0x80000000u) ? ~u : (u | 0x80000000u);   // monotone float -> u32
    return ((unsigned long long)u << 32) | (unsigned long long)(0xFFFFFFFFu - q);
}

// --- 1. deterministic sorted compaction of flag into p1 (flag==1) / q0 (flag==0)
__global__ void compact_kernel(const int* __restrict__ flag, int* __restrict__ q0,
                               int* __restrict__ p1, int* __restrict__ cnt) {
    __shared__ int c1s[256];
    int t = threadIdx.x;
    int f[16]; int n1 = 0;
    #pragma unroll
    for (int j = 0; j < 16; ++j) { f[j] = flag[t*16 + j]; n1 += (f[j] == 1); }
    c1s[t] = n1;
    __syncthreads();
    if (t == 0) {
        int run = 0;
        for (int i = 0; i < 256; ++i) { int v = c1s[i]; c1s[i] = run; run += v; }
        cnt[0] = run;          // n1
        cnt[1] = HW - run;     // n0
    }
    __syncthreads();
    int b1 = c1s[t];
    int b0 = t*16 - c1s[t];
    for (int j = 0; j < 16; ++j) {
        int i = t*16 + j;
        if (f[j] == 1) p1[b1++] = i; else q0[b0++] = i;
    }
}

// --- 2. inv norms of latter columns
__global__ void norm_kernel(const float* __restrict__ x, float* __restrict__ invn) {
    int b = blockIdx.y;
    int q = blockIdx.x * 256 + threadIdx.x;
    const float* lf = x + ((size_t)b * NC + C2) * HW + q;
    float s = 0.f;
    #pragma unroll 8
    for (int c = 0; c < C2; ++c) {
        float v = lf[c * HW];
        s = fmaf(v, v, s);
    }
    invn[b * HW + q] = 1.0f / fmaxf(sqrtf(s), 1e-8f);
}

// --- 3. cos + argmax over unmasked q, merged via packed atomicMax
//     grid: (HW/PT tiles, 8 q-chunks of 512, NB); chunks >= n0/512 exit.
//     ff tile staged in TWO c-halves of 128 so LDS = 16.5 KB (R4's 33 KB
//     capped residency at ~2 blocks/CU -> 22% occupancy, latency-bound).
//     VGPR (~100) now caps at 5 blocks/CU = 62% occ.
//     NOTE: no min-waves clamp in launch_bounds — (256,4) forced VGPR=64
//     and spilled acc[8][8] to scratch (13 GB HBM, 7x regression in R3).
__global__ void __launch_bounds__(256) argmax_kernel(
        const float* __restrict__ x, const float* __restrict__ invn,
        const int* __restrict__ q0, const int* __restrict__ p1,
        const int* __restrict__ cnt, unsigned long long* __restrict__ packed) {
    int tile  = blockIdx.x;
    int chunk = blockIdx.y;
    int b     = blockIdx.z;
    int n1 = cnt[0], n0 = cnt[1];
    if (tile * PT >= n1) return;
    if ((chunk << 9) >= n0) return;

    __shared__ float sff[128][PT];   // ff half-tile: [c][p] 16 KB
    __shared__ int   sp[PT];

    int t = threadIdx.x;
    if (t < PT) sp[t] = (tile * PT + t < n1) ? p1[tile * PT + t] : -1;

    const float* xb = x + (size_t)b * NC * HW;

    int tp = t >> 6;   // wave id -> 8-p sub-tile
    int tq = t & 63;   // lane    -> q
    const float* lfb = xb + C2 * HW;

    int qi[8], qj[8];
    #pragma unroll
    for (int j = 0; j < 8; ++j) {
        qi[j] = (chunk << 9) + (j << 6) + tq;
        qj[j] = (qi[j] < n0) ? q0[qi[j]] : 0;
    }

    float acc[8][8];
    #pragma unroll
    for (int pi = 0; pi < 8; ++pi)
        #pragma unroll
        for (int j = 0; j < 8; ++j) acc[pi][j] = 0.f;

    const float* row = lfb;
    float bv[8];
    #pragma unroll
    for (int j = 0; j < 8; ++j) bv[j] = row[qj[j]];

    for (int h = 0; h < 2; ++h) {
        __syncthreads();   // h=0: sp visible; h=1: all waves done reading sff
        #pragma unroll 4
        for (int k = 0; k < 16; ++k) {      // 4096 elems / 256 threads
            int i = t + (k << 8);
            int c = i >> 5, j = i & 31;
            int p = sp[j];
            sff[c][j] = (p >= 0) ? xb[(h * 128 + c) * HW + p] : 0.f;
        }
        __syncthreads();

        #pragma unroll 2
        for (int cc = 0; cc < 128; ++cc) {
            int cglob = h * 128 + cc;
            // prefetch next c-row's gathers (clamped at the global last row
            // to avoid reading past the end of batch b's data)
            const float* prow = (cglob < 255) ? (row + HW) : row;
            float bvn[8];
            #pragma unroll
            for (int j = 0; j < 8; ++j) bvn[j] = prow[qj[j]];
            const float4* arow = (const float4*)&sff[cc][tp * 8];
            float4 a0 = arow[0], a1 = arow[1];
            float av[8] = {a0.x, a0.y, a0.z, a0.w, a1.x, a1.y, a1.z, a1.w};
            #pragma unroll
            for (int pi = 0; pi < 8; ++pi)
                #pragma unroll
                for (int j = 0; j < 8; ++j)
                    acc[pi][j] = fmaf(av[pi], bv[j], acc[pi][j]);
            #pragma unroll
            for (int j = 0; j < 8; ++j) bv[j] = bvn[j];
            row = prow;
        }
    }

    float best[8];
    int   bq[8];
    #pragma unroll
    for (int pi = 0; pi < 8; ++pi) { best[pi] = -INFINITY; bq[pi] = 0x7FFFFFFF; }

    #pragma unroll
    for (int j = 0; j < 8; ++j) {
        if (qi[j] >= n0) continue;
        float sc = invn[b * HW + qj[j]];
        #pragma unroll
        for (int pi = 0; pi < 8; ++pi) {
            float cv = acc[pi][j] * sc;
            if (cv > best[pi] || (cv == best[pi] && qj[j] < bq[pi])) {
                best[pi] = cv; bq[pi] = qj[j];
            }
        }
    }

    // wave reduce (all 64 lanes share the same 8 p's)
    #pragma unroll
    for (int m = 1; m < 64; m <<= 1) {
        #pragma unroll
        for (int pi = 0; pi < 8; ++pi) {
            float ov = __shfl_xor(best[pi], m);
            int   oq = __shfl_xor(bq[pi], m);
            if (ov > best[pi] || (ov == best[pi] && oq < bq[pi])) {
                best[pi] = ov; bq[pi] = oq;
            }
        }
    }
    if (tq == 0) {
        #pragma unroll
        for (int pi = 0; pi < 8; ++pi) {
            int p = (tile * PT + tp * 8 + pi < n1) ? p1[tile * PT + tp * 8 + pi] : -1;
            if (p >= 0)
                atomicMax(&packed[(size_t)b * HW + p], mkkey(best[pi], (unsigned)bq[pi]));
        }
    }
}

// --- 4. decode packed keys -> idx
__global__ void decode_kernel(const unsigned long long* __restrict__ packed,
                              const int* __restrict__ flag, int* __restrict__ idx) {
    int b = blockIdx.y, p = blockIdx.x * 256 + threadIdx.x;
    int q = 0;
    if (flag[p] == 1) {
        unsigned low = (unsigned)(packed[(size_t)b * HW + p] & 0xFFFFFFFFull);
        q = (int)((0xFFFFFFFFu - low) & (HW - 1));
    }
    idx[b * HW + p] = q;
}

// --- 5. copy former+latter -> out channels [0,512)
__global__ void copy_kernel(const float4* __restrict__ x4, float4* __restrict__ out4) {
    size_t i = (size_t)blockIdx.x * 256 + threadIdx.x;
    if (i >= (size_t)NB * NC * (HW / 4)) return;
    size_t p4 = i & 1023;
    size_t c  = (i >> 10) & 511;
    size_t b  = i >> 19;
    out4[(b * 768 + c) * 1024 + p4] = x4[i];
}

// --- 6. shift writeback: out[b, 512+c, p] = flag[p] ? lf[b, c, idx[b,p]] : 0
__global__ void shift_kernel(const float* __restrict__ x, const int* __restrict__ flag,
                             const int* __restrict__ idx, float* __restrict__ out) {
    int cc = blockIdx.x, b = blockIdx.y;
    const float* lfrow = x + ((size_t)b * NC + C2 + cc) * HW;
    float*       orow  = out + ((size_t)b * 768 + 512 + cc) * HW;
    const int*   idxb  = idx + b * HW;
    for (int p = threadIdx.x; p < HW; p += 256) {
        float v = 0.f;
        if (flag[p] == 1) v = lfrow[idxb[p]];
        orow[p] = v;
    }
}

extern "C" void kernel_launch(void* const* d_in, const int* in_sizes, int n_in,
                              void* d_out, int out_size, void* d_ws, size_t ws_size,
                              hipStream_t stream) {
    const float* x    = (const float*)d_in[0];
    const int*   flag = (const int*)d_in[1];
    float*       out  = (float*)d_out;
    char*        ws   = (char*)d_ws;

    unsigned long long* packed = (unsigned long long*)(ws + WS_PACKED);
    float* invn = (float*)(ws + WS_INVN);
    int*   q0   = (int*)(ws + WS_Q0);
    int*   p1   = (int*)(ws + WS_P1);
    int*   cnt  = (int*)(ws + WS_CNT);
    int*   idx  = (int*)(ws + WS_IDX);

    hipMemsetAsync(packed, 0, (size_t)NB * HW * sizeof(unsigned long long), stream);

    compact_kernel<<<1, 256, 0, stream>>>(flag, q0, p1, cnt);
    norm_kernel<<<dim3(HW / 256, NB), 256, 0, stream>>>(x, invn);
    copy_kernel<<<(NB * NC * (HW / 4) + 255) / 256, 256, 0, stream>>>((const float4*)x, (float4*)out);
    argmax_kernel<<<dim3(HW / PT, 8, NB), 256, 0, stream>>>(x, invn, q0, p1, cnt, packed);
    decode_kernel<<<dim3(HW / 256, NB), 256, 0, stream>>>(packed, flag, idx);
    shift_kernel<<<dim3(C2, NB), 256, 0, stream>>>(x, flag, idx, out);
}